// Round 3
// baseline (365.057 us; speedup 1.0000x reference)
//
#include <hip/hip_runtime.h>
#include <hip/hip_bf16.h>
#include <cstddef>
#include <cstdint>

#define DM 512
#define DS 64
#define L_SEQ 8192
#define NB 8
#define M_ROWS (NB * L_SEQ)      // 65536
#define LN_EPS 1e-3f
#define NCHUNK 256
#define LCH 32                   // NCHUNK * LCH == L_SEQ

typedef __attribute__((ext_vector_type(8))) short short8;
typedef __attribute__((ext_vector_type(4))) float f32x4;
using bf16 = __hip_bfloat16;

__device__ __forceinline__ unsigned short f2bf(float f) {
    bf16 h = __float2bfloat16(f);
    return *reinterpret_cast<unsigned short*>(&h);
}
// LDS XOR swizzle (T2): spread row-major column reads across banks
__device__ __forceinline__ int swz(int row, int bytecol) { return bytecol ^ ((row & 7) << 4); }

// ---------------- merged weight transpose + bf16 convert ----------------
__global__ __launch_bounds__(256) void wtrans_all(const float* __restrict__ W_in,
                                                  const float* __restrict__ W_xs,
                                                  const float* __restrict__ W_so,
                                                  const float* __restrict__ W_out,
                                                  unsigned short* __restrict__ WinT,
                                                  unsigned short* __restrict__ WxsT,
                                                  unsigned short* __restrict__ WsoT,
                                                  unsigned short* __restrict__ WoutT)
{
    int i = blockIdx.x * 256 + threadIdx.x;
    if (i < 262144) {                       // W_in 512x512 -> WinT[n][k]
        int k = i >> 9, n = i & 511;
        WinT[n * 512 + k] = f2bf(W_in[i]);
    } else if (i < 294912) {                // W_xs 512x64 -> WxsT[n][k], n<64,k<512
        int j = i - 262144; int k = j >> 6, n = j & 63;
        WxsT[n * 512 + k] = f2bf(W_xs[j]);
    } else if (i < 327680) {                // W_so 64x512 -> WsoT[n][k], n<512,k<64
        int j = i - 294912; int k = j >> 9, n = j & 511;
        WsoT[n * 64 + k] = f2bf(W_so[j]);
    } else if (i < 589824) {                // W_out 512x512 -> WoutT[n][k]
        int j = i - 327680; int k = j >> 9, n = j & 511;
        WoutT[n * 512 + k] = f2bf(W_out[j]);
    }
}

// ---------------- fused LN + (z = xn@W_in + b_in) + (xs = z@W_xs) ----------------
// 64 rows/block, 4 waves (2x2). xn tile in LDS; weights read from L2 per-fragment.
__global__ __launch_bounds__(256) void fused_ln_g2_g3(const float* __restrict__ x,
                                                      const float* __restrict__ gamma,
                                                      const float* __restrict__ beta,
                                                      const unsigned short* __restrict__ WinT,
                                                      const float* __restrict__ b_in,
                                                      const unsigned short* __restrict__ WxsT,
                                                      unsigned short* __restrict__ z,
                                                      float* __restrict__ xs)
{
    __shared__ unsigned short As[64 * 512];   // 64 KB, row stride 1024B, swizzled
    __shared__ unsigned short Zs[64 * 128];   // 16 KB, row stride 256B, swizzled
    const int tid = threadIdx.x;
    const int lane = tid & 63, wid = tid >> 6;
    const int fr = lane & 15, fq = lane >> 4;
    const int wr = wid >> 1, wc = wid & 1;
    const size_t bm0 = (size_t)blockIdx.x * 64;

    // ---- LN phase: each wave normalizes 16 rows into LDS (bf16, swizzled) ----
    {
        const float4* g4 = (const float4*)gamma;
        const float4* b4 = (const float4*)beta;
        float4 g0 = g4[lane], g1 = g4[lane + 64];
        float4 bb0 = b4[lane], bb1 = b4[lane + 64];
        for (int it = 0; it < 16; ++it) {
            int r = wid * 16 + it;
            const float4* xr = (const float4*)(x + (bm0 + r) * DM);
            float4 v0 = xr[lane], v1 = xr[lane + 64];
            float s  = v0.x + v0.y + v0.z + v0.w + v1.x + v1.y + v1.z + v1.w;
            float s2 = v0.x*v0.x + v0.y*v0.y + v0.z*v0.z + v0.w*v0.w
                     + v1.x*v1.x + v1.y*v1.y + v1.z*v1.z + v1.w*v1.w;
            #pragma unroll
            for (int off = 32; off > 0; off >>= 1) {
                s  += __shfl_xor(s,  off);
                s2 += __shfl_xor(s2, off);
            }
            float mu  = s * (1.0f / DM);
            float var = s2 * (1.0f / DM) - mu * mu;
            float rs  = rsqrtf(var + LN_EPS);
            uint2 p0, p1;
            p0.x = (uint32_t)f2bf((v0.x - mu) * rs * g0.x + bb0.x)
                 | ((uint32_t)f2bf((v0.y - mu) * rs * g0.y + bb0.y) << 16);
            p0.y = (uint32_t)f2bf((v0.z - mu) * rs * g0.z + bb0.z)
                 | ((uint32_t)f2bf((v0.w - mu) * rs * g0.w + bb0.w) << 16);
            p1.x = (uint32_t)f2bf((v1.x - mu) * rs * g1.x + bb1.x)
                 | ((uint32_t)f2bf((v1.y - mu) * rs * g1.y + bb1.y) << 16);
            p1.y = (uint32_t)f2bf((v1.z - mu) * rs * g1.z + bb1.z)
                 | ((uint32_t)f2bf((v1.w - mu) * rs * g1.w + bb1.w) << 16);
            *(uint2*)((char*)As + r * 1024 + swz(r, lane * 8))       = p0;
            *(uint2*)((char*)As + r * 1024 + swz(r, 512 + lane * 8)) = p1;
        }
    }
    __syncthreads();

    // ---- GEMM phase: 4 N-chunks of 128 cols ----
    f32x4 xsacc[2][2];
    #pragma unroll
    for (int m = 0; m < 2; ++m)
        #pragma unroll
        for (int n = 0; n < 2; ++n)
            xsacc[m][n] = (f32x4){0.f, 0.f, 0.f, 0.f};

    for (int c = 0; c < 4; ++c) {
        f32x4 zacc[2][4];
        #pragma unroll
        for (int m = 0; m < 2; ++m)
            #pragma unroll
            for (int n = 0; n < 4; ++n)
                zacc[m][n] = (f32x4){0.f, 0.f, 0.f, 0.f};
        // z-GEMM: K=512, no barriers (A in LDS, B from L2)
        #pragma unroll 4
        for (int kk = 0; kk < 16; ++kk) {
            short8 af[2];
            #pragma unroll
            for (int m = 0; m < 2; ++m) {
                int row = wr * 32 + m * 16 + fr;
                af[m] = *(const short8*)((const char*)As + row * 1024 + swz(row, kk * 64 + fq * 16));
            }
            short8 bg[4];
            #pragma unroll
            for (int n = 0; n < 4; ++n) {
                int col = c * 128 + wc * 64 + n * 16 + fr;
                bg[n] = *(const short8*)(WinT + (size_t)col * 512 + kk * 32 + fq * 8);
            }
            #pragma unroll
            for (int m = 0; m < 2; ++m)
                #pragma unroll
                for (int n = 0; n < 4; ++n)
                    zacc[m][n] = __builtin_amdgcn_mfma_f32_16x16x32_bf16(af[m], bg[n], zacc[m][n], 0, 0, 0);
        }
        // epilogue: + b_in, write z (global bf16) and Zs (LDS)
        #pragma unroll
        for (int n = 0; n < 4; ++n) {
            int coll = wc * 64 + n * 16 + fr;
            int colg = c * 128 + coll;
            float bv = b_in[colg];
            #pragma unroll
            for (int m = 0; m < 2; ++m) {
                int rowl = wr * 32 + m * 16 + fq * 4;
                #pragma unroll
                for (int r2 = 0; r2 < 4; ++r2) {
                    unsigned short hv = f2bf(zacc[m][n][r2] + bv);
                    z[(bm0 + rowl + r2) * DM + colg] = hv;
                    *(unsigned short*)((char*)Zs + (rowl + r2) * 256 + swz(rowl + r2, coll * 2)) = hv;
                }
            }
        }
        __syncthreads();
        // xs partial: xs += z_chunk @ W_xs[c*128 .. c*128+127][:]
        #pragma unroll
        for (int kk = 0; kk < 4; ++kk) {
            short8 af2[2];
            #pragma unroll
            for (int m = 0; m < 2; ++m) {
                int row = wr * 32 + m * 16 + fr;
                af2[m] = *(const short8*)((const char*)Zs + row * 256 + swz(row, kk * 64 + fq * 16));
            }
            short8 bg2[2];
            #pragma unroll
            for (int n = 0; n < 2; ++n) {
                int col = wc * 32 + n * 16 + fr;
                bg2[n] = *(const short8*)(WxsT + (size_t)col * 512 + c * 128 + kk * 32 + fq * 8);
            }
            #pragma unroll
            for (int m = 0; m < 2; ++m)
                #pragma unroll
                for (int n = 0; n < 2; ++n)
                    xsacc[m][n] = __builtin_amdgcn_mfma_f32_16x16x32_bf16(af2[m], bg2[n], xsacc[m][n], 0, 0, 0);
        }
        __syncthreads();   // protect Zs before next chunk overwrites
    }
    // write xs (f32)
    #pragma unroll
    for (int n = 0; n < 2; ++n) {
        int colg = wc * 32 + n * 16 + fr;
        #pragma unroll
        for (int m = 0; m < 2; ++m) {
            size_t rowg = bm0 + wr * 32 + m * 16 + fq * 4;
            #pragma unroll
            for (int r2 = 0; r2 < 4; ++r2)
                xs[(rowg + r2) * DS + colg] = xsacc[m][n][r2];
        }
    }
}

// ---------------- fused (t1 = ys@W_so + D*z) + (out = t1@W_out + b_out + x) -----
__global__ __launch_bounds__(256) void fused_g7_g8(const unsigned short* __restrict__ ys,
                                                   const unsigned short* __restrict__ z,
                                                   const unsigned short* __restrict__ WsoT,
                                                   const float* __restrict__ Dv,
                                                   const unsigned short* __restrict__ WoutT,
                                                   const float* __restrict__ b_out,
                                                   const float* __restrict__ x,
                                                   float* __restrict__ out)
{
    __shared__ unsigned short Ys[64 * 64];    // 8 KB, row stride 128B, swizzled
    __shared__ unsigned short T1s[64 * 512];  // 64 KB, row stride 1024B, swizzled
    const int tid = threadIdx.x;
    const int lane = tid & 63, wid = tid >> 6;
    const int fr = lane & 15, fq = lane >> 4;
    const int wr = wid >> 1, wc = wid & 1;
    const size_t bm0 = (size_t)blockIdx.x * 64;

    // load ys tile (reg-staged so we can swizzle)
    #pragma unroll
    for (int p = 0; p < 2; ++p) {
        int idx = (p * 256 + tid) * 8;
        int row = idx >> 6, col = idx & 63;
        short8 v = *(const short8*)(ys + (bm0 + row) * DS + col);
        *(short8*)((char*)Ys + row * 128 + swz(row, col * 2)) = v;
    }
    __syncthreads();

    // G7: t1 = ys @ W_so + D*z, kept in LDS
    for (int c = 0; c < 4; ++c) {
        f32x4 acc[2][4];
        #pragma unroll
        for (int m = 0; m < 2; ++m)
            #pragma unroll
            for (int n = 0; n < 4; ++n)
                acc[m][n] = (f32x4){0.f, 0.f, 0.f, 0.f};
        #pragma unroll
        for (int kk = 0; kk < 2; ++kk) {
            short8 af[2];
            #pragma unroll
            for (int m = 0; m < 2; ++m) {
                int row = wr * 32 + m * 16 + fr;
                af[m] = *(const short8*)((const char*)Ys + row * 128 + swz(row, kk * 64 + fq * 16));
            }
            short8 bg[4];
            #pragma unroll
            for (int n = 0; n < 4; ++n) {
                int col = c * 128 + wc * 64 + n * 16 + fr;
                bg[n] = *(const short8*)(WsoT + (size_t)col * 64 + kk * 32 + fq * 8);
            }
            #pragma unroll
            for (int m = 0; m < 2; ++m)
                #pragma unroll
                for (int n = 0; n < 4; ++n)
                    acc[m][n] = __builtin_amdgcn_mfma_f32_16x16x32_bf16(af[m], bg[n], acc[m][n], 0, 0, 0);
        }
        #pragma unroll
        for (int n = 0; n < 4; ++n) {
            int colg = c * 128 + wc * 64 + n * 16 + fr;
            float dv = Dv[colg];
            #pragma unroll
            for (int m = 0; m < 2; ++m) {
                int rowl = wr * 32 + m * 16 + fq * 4;
                #pragma unroll
                for (int r2 = 0; r2 < 4; ++r2) {
                    float zv = __bfloat162float(((const bf16*)z)[(bm0 + rowl + r2) * DM + colg]);
                    float v = acc[m][n][r2] + dv * zv;
                    *(unsigned short*)((char*)T1s + (rowl + r2) * 1024 + swz(rowl + r2, colg * 2)) = f2bf(v);
                }
            }
        }
    }
    __syncthreads();

    // G8: out = t1 @ W_out + b_out + x
    for (int c = 0; c < 4; ++c) {
        f32x4 acc[2][4];
        #pragma unroll
        for (int m = 0; m < 2; ++m)
            #pragma unroll
            for (int n = 0; n < 4; ++n)
                acc[m][n] = (f32x4){0.f, 0.f, 0.f, 0.f};
        #pragma unroll 4
        for (int kk = 0; kk < 16; ++kk) {
            short8 af[2];
            #pragma unroll
            for (int m = 0; m < 2; ++m) {
                int row = wr * 32 + m * 16 + fr;
                af[m] = *(const short8*)((const char*)T1s + row * 1024 + swz(row, kk * 64 + fq * 16));
            }
            short8 bg[4];
            #pragma unroll
            for (int n = 0; n < 4; ++n) {
                int col = c * 128 + wc * 64 + n * 16 + fr;
                bg[n] = *(const short8*)(WoutT + (size_t)col * 512 + kk * 32 + fq * 8);
            }
            #pragma unroll
            for (int m = 0; m < 2; ++m)
                #pragma unroll
                for (int n = 0; n < 4; ++n)
                    acc[m][n] = __builtin_amdgcn_mfma_f32_16x16x32_bf16(af[m], bg[n], acc[m][n], 0, 0, 0);
        }
        #pragma unroll
        for (int n = 0; n < 4; ++n) {
            int colg = c * 128 + wc * 64 + n * 16 + fr;
            float bo = b_out[colg];
            #pragma unroll
            for (int m = 0; m < 2; ++m) {
                size_t rowg = bm0 + wr * 32 + m * 16 + fq * 4;
                #pragma unroll
                for (int r2 = 0; r2 < 4; ++r2)
                    out[(rowg + r2) * DM + colg] = acc[m][n][r2] + bo + x[(rowg + r2) * DM + colg];
            }
        }
    }
}

// ---------------- SSM scan (chunked, 3 passes) ----------------
__device__ __forceinline__ void ssm_params(const float* A_log, const float* log_delta,
                                           const float* Bv, int n, float& Ab, float& Bb)
{
    float A  = -expf(A_log[n]);
    float dl = log1pf(expf(log_delta[n]));   // softplus
    float dA2 = dl * A * 0.5f;
    float inv = 1.0f / (1.0f - dA2);
    Ab = (1.0f + dA2) * inv;
    Bb = dl * inv * Bv[n];
}

__global__ __launch_bounds__(64) void scan_pass1(const float* __restrict__ xs,
                                                 const float* __restrict__ A_log,
                                                 const float* __restrict__ log_delta,
                                                 const float* __restrict__ Bv,
                                                 float* __restrict__ carry)
{
    int b = blockIdx.x / NCHUNK;
    int c = blockIdx.x % NCHUNK;
    int n = threadIdx.x;
    float Ab, Bb;
    ssm_params(A_log, log_delta, Bv, n, Ab, Bb);
    size_t base = ((size_t)b * L_SEQ + (size_t)c * LCH) * DS + n;
    float h = 0.0f;
    for (int t = 0; t < LCH; ++t)
        h = Ab * h + Bb * xs[base + (size_t)t * DS];
    carry[((size_t)b * NCHUNK + c) * DS + n] = h;
}

__global__ __launch_bounds__(64) void scan_pass2(const float* __restrict__ A_log,
                                                 const float* __restrict__ log_delta,
                                                 const float* __restrict__ Bv,
                                                 const float* __restrict__ carry,
                                                 float* __restrict__ hin)
{
    int b = blockIdx.x;
    int n = threadIdx.x;
    float Ab, Bb;
    ssm_params(A_log, log_delta, Bv, n, Ab, Bb);
    float powA = powf(Ab, (float)LCH);
    float h = 0.0f;
    for (int c = 0; c < NCHUNK; ++c) {
        size_t idx = ((size_t)b * NCHUNK + c) * DS + n;
        hin[idx] = h;
        h = powA * h + carry[idx];
    }
}

__global__ __launch_bounds__(64) void scan_pass3(const float* __restrict__ xs,
                                                 const float* __restrict__ A_log,
                                                 const float* __restrict__ log_delta,
                                                 const float* __restrict__ Bv,
                                                 const float* __restrict__ Cv,
                                                 const float* __restrict__ hin,
                                                 unsigned short* __restrict__ ys)
{
    int b = blockIdx.x / NCHUNK;
    int c = blockIdx.x % NCHUNK;
    int n = threadIdx.x;
    float Ab, Bb;
    ssm_params(A_log, log_delta, Bv, n, Ab, Bb);
    float Cn = Cv[n];
    size_t base = ((size_t)b * L_SEQ + (size_t)c * LCH) * DS + n;
    float h = hin[((size_t)b * NCHUNK + c) * DS + n];
    for (int t = 0; t < LCH; ++t) {
        h = Ab * h + Bb * xs[base + (size_t)t * DS];
        ys[base + (size_t)t * DS] = f2bf(Cn * h);
    }
}

// ---------------- launcher ----------------
extern "C" void kernel_launch(void* const* d_in, const int* in_sizes, int n_in,
                              void* d_out, int out_size, void* d_ws, size_t ws_size,
                              hipStream_t stream)
{
    const float* x         = (const float*)d_in[0];
    const float* ln_gamma  = (const float*)d_in[1];
    const float* ln_beta   = (const float*)d_in[2];
    const float* W_in      = (const float*)d_in[3];
    const float* b_in      = (const float*)d_in[4];
    const float* W_xs      = (const float*)d_in[5];
    const float* A_log     = (const float*)d_in[6];
    const float* log_delta = (const float*)d_in[7];
    const float* Bv        = (const float*)d_in[8];
    const float* Cv        = (const float*)d_in[9];
    const float* Dv        = (const float*)d_in[10];
    const float* W_so      = (const float*)d_in[11];
    const float* W_out     = (const float*)d_in[12];
    const float* b_out     = (const float*)d_in[13];
    float* out = (float*)d_out;

    const size_t M = M_ROWS;
    float*          xs_f = (float*)d_ws;                      // M*64 f32
    unsigned short* z_b  = (unsigned short*)(xs_f + M * DS);  // M*512 bf16
    unsigned short* ys_b = z_b + M * (size_t)DM;              // M*64 bf16
    unsigned short* WinT = ys_b + M * (size_t)DS;             // 512*512
    unsigned short* WxsT = WinT + (size_t)DM * DM;            // 64*512
    unsigned short* WsoT = WxsT + (size_t)DS * DM;            // 512*64
    unsigned short* WoutT= WsoT + (size_t)DM * DS;            // 512*512
    float* carry = (float*)(WoutT + (size_t)DM * DM);         // 8*256*64
    float* hin   = carry + NB * NCHUNK * DS;                  // 8*256*64

    wtrans_all<<<dim3(589824 / 256), dim3(256), 0, stream>>>(W_in, W_xs, W_so, W_out,
                                                             WinT, WxsT, WsoT, WoutT);
    fused_ln_g2_g3<<<dim3(M / 64), dim3(256), 0, stream>>>(x, ln_gamma, ln_beta,
                                                           WinT, b_in, WxsT, z_b, xs_f);
    scan_pass1<<<dim3(NB * NCHUNK), dim3(64), 0, stream>>>(xs_f, A_log, log_delta, Bv, carry);
    scan_pass2<<<dim3(NB), dim3(64), 0, stream>>>(A_log, log_delta, Bv, carry, hin);
    scan_pass3<<<dim3(NB * NCHUNK), dim3(64), 0, stream>>>(xs_f, A_log, log_delta, Bv, Cv, hin, ys_b);
    fused_g7_g8<<<dim3(M / 64), dim3(256), 0, stream>>>(ys_b, z_b, WsoT, Dv, WoutT, b_out, x, out);
}

// Round 4
// 275.436 us; speedup vs baseline: 1.3254x; 1.3254x over previous
//
#include <hip/hip_runtime.h>
#include <hip/hip_bf16.h>
#include <cstddef>
#include <cstdint>

#define DM 512
#define DS 64
#define L_SEQ 8192
#define NB 8
#define M_ROWS (NB * L_SEQ)      // 65536
#define LN_EPS 1e-3f
#define NCHUNK 256
#define LCH 32                   // NCHUNK * LCH == L_SEQ

typedef __attribute__((ext_vector_type(8))) short short8;
typedef __attribute__((ext_vector_type(4))) float f32x4;
using bf16 = __hip_bfloat16;

__device__ __forceinline__ unsigned short f2bf(float f) {
    bf16 h = __float2bfloat16(f);
    return *reinterpret_cast<unsigned short*>(&h);
}

// Pre-swizzle column map: within each 64-element (128B) segment of a row,
// 16B granule index g -> g ^ (row&7). Applied at PRODUCE time in global memory
// so that linear global_load_lds yields a swizzled LDS tile (rule #21).
__device__ __forceinline__ int swzcol(int row, int col) {
    return (col & ~63) | (((((col >> 3) & 7) ^ (row & 7))) << 3) | (col & 7);
}

__device__ __forceinline__ void gload_lds16(const void* g, void* l) {
    __builtin_amdgcn_global_load_lds(
        (const __attribute__((address_space(1))) void*)g,
        (__attribute__((address_space(3))) void*)l, 16, 0, 0);
}

// ---------------- weight transpose + bf16 convert + pre-swizzle ----------------
__global__ __launch_bounds__(256) void wtrans_all(const float* __restrict__ W_in,
                                                  const float* __restrict__ W_xs,
                                                  const float* __restrict__ W_so,
                                                  const float* __restrict__ W_out,
                                                  unsigned short* __restrict__ WinT,
                                                  unsigned short* __restrict__ WxsT,
                                                  unsigned short* __restrict__ WsoT,
                                                  unsigned short* __restrict__ WoutT)
{
    int i = blockIdx.x * 256 + threadIdx.x;
    if (i < 262144) {                       // W_in 512x512 -> WinT[n][k]
        int k = i >> 9, n = i & 511;
        WinT[n * 512 + swzcol(n, k)] = f2bf(W_in[i]);
    } else if (i < 294912) {                // W_xs 512x64 -> WxsT[n<64][k<512]
        int j = i - 262144; int k = j >> 6, n = j & 63;
        WxsT[n * 512 + swzcol(n, k)] = f2bf(W_xs[j]);
    } else if (i < 327680) {                // W_so 64x512 -> WsoT[n<512][k<64]
        int j = i - 294912; int k = j >> 9, n = j & 511;
        WsoT[n * 64 + swzcol(n, k)] = f2bf(W_so[j]);
    } else if (i < 589824) {                // W_out 512x512 -> WoutT[n][k]
        int j = i - 327680; int k = j >> 9, n = j & 511;
        WoutT[n * 512 + swzcol(n, k)] = f2bf(W_out[j]);
    }
}

// ---------------- LayerNorm: one wave per row, pre-swizzled bf16 out -----------
__global__ __launch_bounds__(64) void ln_kernel(const float* __restrict__ x,
                                                const float* __restrict__ gamma,
                                                const float* __restrict__ beta,
                                                unsigned short* __restrict__ xn)
{
    size_t row = blockIdx.x;
    int lane = threadIdx.x;                       // 0..63, covers cols lane*8..+7
    const float4* xr = (const float4*)(x + row * DM);
    float4 v0 = xr[lane * 2];
    float4 v1 = xr[lane * 2 + 1];
    float s  = v0.x + v0.y + v0.z + v0.w + v1.x + v1.y + v1.z + v1.w;
    float s2 = v0.x*v0.x + v0.y*v0.y + v0.z*v0.z + v0.w*v0.w
             + v1.x*v1.x + v1.y*v1.y + v1.z*v1.z + v1.w*v1.w;
    #pragma unroll
    for (int off = 32; off > 0; off >>= 1) {
        s  += __shfl_xor(s,  off);
        s2 += __shfl_xor(s2, off);
    }
    float mu  = s * (1.0f / DM);
    float var = s2 * (1.0f / DM) - mu * mu;
    float rs  = rsqrtf(var + LN_EPS);
    const float4* g4 = (const float4*)gamma;
    const float4* b4 = (const float4*)beta;
    float4 g0 = g4[lane * 2], g1 = g4[lane * 2 + 1];
    float4 bb0 = b4[lane * 2], bb1 = b4[lane * 2 + 1];
    short8 o;
    o[0] = (short)f2bf((v0.x - mu) * rs * g0.x + bb0.x);
    o[1] = (short)f2bf((v0.y - mu) * rs * g0.y + bb0.y);
    o[2] = (short)f2bf((v0.z - mu) * rs * g0.z + bb0.z);
    o[3] = (short)f2bf((v0.w - mu) * rs * g0.w + bb0.w);
    o[4] = (short)f2bf((v1.x - mu) * rs * g1.x + bb1.x);
    o[5] = (short)f2bf((v1.y - mu) * rs * g1.y + bb1.y);
    o[6] = (short)f2bf((v1.z - mu) * rs * g1.z + bb1.z);
    o[7] = (short)f2bf((v1.w - mu) * rs * g1.w + bb1.w);
    int g = (lane & 7) ^ ((int)row & 7);          // swizzled granule
    *(short8*)(xn + row * DM + (lane >> 3) * 64 + g * 8) = o;
}

// ---------------- epilogue helpers ----------------
__device__ __forceinline__ float aux_to_float(float x) { return x; }
__device__ __forceinline__ float aux_to_float(bf16 x)  { return __bfloat162float(x); }
__device__ __forceinline__ void store_out(float* C, size_t i, float v) { C[i] = v; }
__device__ __forceinline__ void store_out(bf16* C, size_t i, float v)  { C[i] = __float2bfloat16(v); }

// ---------------- pipelined MFMA GEMM ----------------
// C = A(MxK) @ BT^T (BT is NxK) + epilogue. A, BT pre-swizzled bf16.
// BM=128, BK=64, 512 threads (8 waves, WR x WC grid), double-buffered LDS,
// one barrier per K-step (T3 minimum recipe).
template<int BN, int WR, int WC, typename OutT, typename AuxT,
         bool HB, bool HA, bool HS, bool SWZO, bool AUXSWZ>
__global__ __launch_bounds__(512, 4) void gemm_pipe(const unsigned short* __restrict__ A,
                                                    const unsigned short* __restrict__ BT,
                                                    const float* __restrict__ bias,
                                                    const AuxT* __restrict__ aux,
                                                    const float* __restrict__ scale,
                                                    OutT* __restrict__ C,
                                                    int M, int N, int K)
{
    constexpr int BM = 128, BK = 64;
    constexpr int MF = BM / (16 * WR), NF = BN / (16 * WC);
    constexpr int ABYTES = BM * 128;          // 16 KB
    constexpr int BBYTES = BN * 128;
    constexpr int AINSTR = ABYTES / 8192;     // 512 thr x 16B = 8 KB per instr
    constexpr int BINSTR = BBYTES / 8192;
    __shared__ unsigned char LDS[2][ABYTES + BBYTES];

    const int tid = threadIdx.x;
    const int lane = tid & 63, w = tid >> 6;
    const int fr = lane & 15, fq = lane >> 4;
    const int wr = w % WR, wc = w / WR;
    const size_t bm0 = (size_t)blockIdx.x * BM;
    const int bn0 = blockIdx.y * BN;
    const int nk = K / BK;

    f32x4 acc[MF][NF];
    #pragma unroll
    for (int m = 0; m < MF; ++m)
        #pragma unroll
        for (int n = 0; n < NF; ++n)
            acc[m][n] = (f32x4){0.f, 0.f, 0.f, 0.f};

    auto stage = [&](int buf, int k0) {
        #pragma unroll
        for (int j = 0; j < AINSTR; ++j) {
            int row = j * 64 + (tid >> 3);                      // per-lane (global addr)
            gload_lds16(A + (bm0 + row) * (size_t)K + (size_t)k0 * 64 + (tid & 7) * 8,
                        &LDS[buf][j * 8192 + w * 1024]);        // wave-uniform base
        }
        #pragma unroll
        for (int j = 0; j < BINSTR; ++j) {
            int row = j * 64 + (tid >> 3);
            gload_lds16(BT + (size_t)(bn0 + row) * K + (size_t)k0 * 64 + (tid & 7) * 8,
                        &LDS[buf][ABYTES + j * 8192 + w * 1024]);
        }
    };

    auto compute = [&](int buf) {
        #pragma unroll
        for (int h = 0; h < 2; ++h) {                           // two K=32 slices in BK=64
            short8 af[MF], bfr[NF];
            #pragma unroll
            for (int m = 0; m < MF; ++m) {
                int row = wr * (BM / WR) + m * 16 + fr;
                int g = (h * 4 + fq) ^ (row & 7);
                af[m] = *(const short8*)&LDS[buf][row * 128 + g * 16];
            }
            #pragma unroll
            for (int n = 0; n < NF; ++n) {
                int col = wc * (BN / WC) + n * 16 + fr;
                int g = (h * 4 + fq) ^ (col & 7);
                bfr[n] = *(const short8*)&LDS[buf][ABYTES + col * 128 + g * 16];
            }
            #pragma unroll
            for (int m = 0; m < MF; ++m)
                #pragma unroll
                for (int n = 0; n < NF; ++n)
                    acc[m][n] = __builtin_amdgcn_mfma_f32_16x16x32_bf16(af[m], bfr[n], acc[m][n], 0, 0, 0);
        }
    };

    stage(0, 0);
    __syncthreads();
    int cur = 0;
    for (int t = 0; t < nk; ++t) {
        if (t + 1 < nk) stage(cur ^ 1, t + 1);   // loads fly under compute
        compute(cur);
        if (t + 1 < nk) { __syncthreads(); cur ^= 1; }   // one drain+barrier per K-step
    }

    // epilogue
    #pragma unroll
    for (int n = 0; n < NF; ++n) {
        int coll = wc * (BN / WC) + n * 16 + fr;
        int colg = bn0 + coll;
        float bv = HB ? bias[colg] : 0.f;
        float sv = HS ? scale[colg] : 1.f;
        #pragma unroll
        for (int m = 0; m < MF; ++m) {
            int rowl = wr * (BM / WR) + m * 16 + fq * 4;
            #pragma unroll
            for (int r = 0; r < 4; ++r) {
                size_t row = bm0 + rowl + r;
                float v = acc[m][n][r] + bv;
                if (HA) {
                    size_t ac = AUXSWZ ? (size_t)swzcol(rowl + r, colg) : (size_t)colg;
                    v += sv * aux_to_float(aux[row * (size_t)N + ac]);
                }
                size_t oc = SWZO ? (size_t)swzcol(rowl + r, colg) : (size_t)colg;
                store_out(C, row * (size_t)N + oc, v);
            }
        }
    }
}

// ---------------- SSM scan (chunked, 3 passes) ----------------
__device__ __forceinline__ void ssm_params(const float* A_log, const float* log_delta,
                                           const float* Bv, int n, float& Ab, float& Bb)
{
    float A  = -expf(A_log[n]);
    float dl = log1pf(expf(log_delta[n]));   // softplus
    float dA2 = dl * A * 0.5f;
    float inv = 1.0f / (1.0f - dA2);
    Ab = (1.0f + dA2) * inv;
    Bb = dl * inv * Bv[n];
}

__global__ __launch_bounds__(64) void scan_pass1(const float* __restrict__ xs,
                                                 const float* __restrict__ A_log,
                                                 const float* __restrict__ log_delta,
                                                 const float* __restrict__ Bv,
                                                 float* __restrict__ carry)
{
    int b = blockIdx.x / NCHUNK;
    int c = blockIdx.x % NCHUNK;
    int n = threadIdx.x;
    float Ab, Bb;
    ssm_params(A_log, log_delta, Bv, n, Ab, Bb);
    size_t base = ((size_t)b * L_SEQ + (size_t)c * LCH) * DS + n;
    float h = 0.0f;
    for (int t = 0; t < LCH; ++t)
        h = Ab * h + Bb * xs[base + (size_t)t * DS];
    carry[((size_t)b * NCHUNK + c) * DS + n] = h;
}

__global__ __launch_bounds__(64) void scan_pass2(const float* __restrict__ A_log,
                                                 const float* __restrict__ log_delta,
                                                 const float* __restrict__ Bv,
                                                 const float* __restrict__ carry,
                                                 float* __restrict__ hin)
{
    int b = blockIdx.x;
    int n = threadIdx.x;
    float Ab, Bb;
    ssm_params(A_log, log_delta, Bv, n, Ab, Bb);
    float powA = powf(Ab, (float)LCH);
    float h = 0.0f;
    for (int c = 0; c < NCHUNK; ++c) {
        size_t idx = ((size_t)b * NCHUNK + c) * DS + n;
        hin[idx] = h;
        h = powA * h + carry[idx];
    }
}

// ys written PRE-SWIZZLED (it is the A-operand of G7)
__global__ __launch_bounds__(64) void scan_pass3(const float* __restrict__ xs,
                                                 const float* __restrict__ A_log,
                                                 const float* __restrict__ log_delta,
                                                 const float* __restrict__ Bv,
                                                 const float* __restrict__ Cv,
                                                 const float* __restrict__ hin,
                                                 unsigned short* __restrict__ ys)
{
    int b = blockIdx.x / NCHUNK;
    int c = blockIdx.x % NCHUNK;
    int n = threadIdx.x;
    float Ab, Bb;
    ssm_params(A_log, log_delta, Bv, n, Ab, Bb);
    float Cn = Cv[n];
    size_t base = ((size_t)b * L_SEQ + (size_t)c * LCH) * DS + n;
    size_t rowbase = ((size_t)b * L_SEQ + (size_t)c * LCH) * DS;
    float h = hin[((size_t)b * NCHUNK + c) * DS + n];
    for (int t = 0; t < LCH; ++t) {
        h = Ab * h + Bb * xs[base + (size_t)t * DS];
        int col = (((n >> 3) ^ (t & 7)) << 3) | (n & 7);   // row&7 == t&7 (LCH%8==0)
        ys[rowbase + (size_t)t * DS + col] = f2bf(Cn * h);
    }
}

// ---------------- launcher ----------------
extern "C" void kernel_launch(void* const* d_in, const int* in_sizes, int n_in,
                              void* d_out, int out_size, void* d_ws, size_t ws_size,
                              hipStream_t stream)
{
    const float* x         = (const float*)d_in[0];
    const float* ln_gamma  = (const float*)d_in[1];
    const float* ln_beta   = (const float*)d_in[2];
    const float* W_in      = (const float*)d_in[3];
    const float* b_in      = (const float*)d_in[4];
    const float* W_xs      = (const float*)d_in[5];
    const float* A_log     = (const float*)d_in[6];
    const float* log_delta = (const float*)d_in[7];
    const float* Bv        = (const float*)d_in[8];
    const float* Cv        = (const float*)d_in[9];
    const float* Dv        = (const float*)d_in[10];
    const float* W_so      = (const float*)d_in[11];
    const float* W_out     = (const float*)d_in[12];
    const float* b_out     = (const float*)d_in[13];
    float* out = (float*)d_out;

    const size_t M = M_ROWS;
    float*          xs_f = (float*)d_ws;                      // M*64 f32
    unsigned short* xn_b = (unsigned short*)(xs_f + M * DS);  // M*512 bf16 (reused as t1)
    unsigned short* z_b  = xn_b + M * (size_t)DM;             // M*512 bf16
    unsigned short* ys_b = z_b + M * (size_t)DM;              // M*64 bf16
    unsigned short* WinT = ys_b + M * (size_t)DS;             // 512*512
    unsigned short* WxsT = WinT + (size_t)DM * DM;            // 64*512
    unsigned short* WsoT = WxsT + (size_t)DS * DM;            // 512*64
    unsigned short* WoutT= WsoT + (size_t)DM * DS;            // 512*512
    float* carry = (float*)(WoutT + (size_t)DM * DM);         // 8*256*64
    float* hin   = carry + NB * NCHUNK * DS;                  // 8*256*64
    unsigned short* t1_b = xn_b;                              // xn dead after G2

    wtrans_all<<<dim3(589824 / 256), dim3(256), 0, stream>>>(W_in, W_xs, W_so, W_out,
                                                             WinT, WxsT, WsoT, WoutT);
    // LN -> xn (pre-swizzled bf16)
    ln_kernel<<<dim3((unsigned)M), dim3(64), 0, stream>>>(x, ln_gamma, ln_beta, xn_b);
    // G2: z = xn @ W_in + b_in   (bf16, pre-swizzled out)
    gemm_pipe<128, 2, 4, bf16, float, true, false, false, true, false>
        <<<dim3(M / 128, DM / 128), dim3(512), 0, stream>>>(xn_b, WinT, b_in, nullptr, nullptr,
                                                            (bf16*)z_b, (int)M, DM, DM);
    // G3: xs = z @ W_xs          (f32 out, plain)
    gemm_pipe<64, 4, 2, float, float, false, false, false, false, false>
        <<<dim3(M / 128, 1), dim3(512), 0, stream>>>(z_b, WxsT, nullptr, nullptr, nullptr,
                                                     xs_f, (int)M, DS, DM);
    // scan
    scan_pass1<<<dim3(NB * NCHUNK), dim3(64), 0, stream>>>(xs_f, A_log, log_delta, Bv, carry);
    scan_pass2<<<dim3(NB), dim3(64), 0, stream>>>(A_log, log_delta, Bv, carry, hin);
    scan_pass3<<<dim3(NB * NCHUNK), dim3(64), 0, stream>>>(xs_f, A_log, log_delta, Bv, Cv, hin, ys_b);
    // G7: t1 = ys @ W_so + D*z   (K=64, bf16 pre-swizzled out; z read de-swizzled)
    gemm_pipe<128, 2, 4, bf16, bf16, false, true, true, true, true>
        <<<dim3(M / 128, DM / 128), dim3(512), 0, stream>>>(ys_b, WsoT, nullptr, (const bf16*)z_b,
                                                            Dv, (bf16*)t1_b, (int)M, DM, DS);
    // G8: out = t1 @ W_out + b_out + x  (f32 out, plain)
    gemm_pipe<128, 2, 4, float, float, true, true, false, false, false>
        <<<dim3(M / 128, DM / 128), dim3(512), 0, stream>>>(t1_b, WoutT, b_out, x, nullptr,
                                                            out, (int)M, DM, DM);
}

// Round 5
// 261.097 us; speedup vs baseline: 1.3982x; 1.0549x over previous
//
#include <hip/hip_runtime.h>
#include <hip/hip_bf16.h>
#include <cstddef>
#include <cstdint>

#define DM 512
#define DS 64
#define L_SEQ 8192
#define NB 8
#define M_ROWS (NB * L_SEQ)      // 65536
#define LN_EPS 1e-3f
#define NCHUNK 256
#define LCH 32                   // NCHUNK * LCH == L_SEQ

typedef __attribute__((ext_vector_type(8))) short short8;
typedef __attribute__((ext_vector_type(4))) float f32x4;
using bf16 = __hip_bfloat16;

__device__ __forceinline__ unsigned short f2bf(float f) {
    bf16 h = __float2bfloat16(f);
    return *reinterpret_cast<unsigned short*>(&h);
}

// Pre-swizzle column map: within each 64-element (128B) segment of a row,
// 16B granule index g -> g ^ (row&7), applied at PRODUCE time in global memory
// (rule #21: linear global_load_lds + swizzled ds_read).
__device__ __forceinline__ int swzcol(int row, int col) {
    return (col & ~63) | (((((col >> 3) & 7) ^ (row & 7))) << 3) | (col & 7);
}

__device__ __forceinline__ void gload_lds16(const void* g, void* l) {
    __builtin_amdgcn_global_load_lds(
        (const __attribute__((address_space(1))) void*)g,
        (__attribute__((address_space(3))) void*)l, 16, 0, 0);
}

template<int N> __device__ __forceinline__ void wait_vm() {
    static_assert(N == 0 || N == 3 || N == 4 || N == 32 || N == 35 || N == 36, "");
    if constexpr (N == 0)       asm volatile("s_waitcnt vmcnt(0)" ::: "memory");
    else if constexpr (N == 3)  asm volatile("s_waitcnt vmcnt(3)" ::: "memory");
    else if constexpr (N == 4)  asm volatile("s_waitcnt vmcnt(4)" ::: "memory");
    else if constexpr (N == 32) asm volatile("s_waitcnt vmcnt(32)" ::: "memory");
    else if constexpr (N == 35) asm volatile("s_waitcnt vmcnt(35)" ::: "memory");
    else if constexpr (N == 36) asm volatile("s_waitcnt vmcnt(36)" ::: "memory");
}

__device__ __forceinline__ void block_barrier() {
    asm volatile("" ::: "memory");
    __builtin_amdgcn_s_barrier();
    asm volatile("" ::: "memory");
}

// ---------------- weight transpose + bf16 convert + pre-swizzle ----------------
__global__ __launch_bounds__(256) void wtrans_all(const float* __restrict__ W_in,
                                                  const float* __restrict__ W_xs,
                                                  const float* __restrict__ W_so,
                                                  const float* __restrict__ W_out,
                                                  unsigned short* __restrict__ WinT,
                                                  unsigned short* __restrict__ WxsT,
                                                  unsigned short* __restrict__ WsoT,
                                                  unsigned short* __restrict__ WoutT)
{
    int i = blockIdx.x * 256 + threadIdx.x;
    if (i < 262144) {                       // W_in 512x512 -> WinT[n][k]
        int k = i >> 9, n = i & 511;
        WinT[n * 512 + swzcol(n, k)] = f2bf(W_in[i]);
    } else if (i < 294912) {                // W_xs 512x64 -> WxsT[n<64][k<512]
        int j = i - 262144; int k = j >> 6, n = j & 63;
        WxsT[n * 512 + swzcol(n, k)] = f2bf(W_xs[j]);
    } else if (i < 327680) {                // W_so 64x512 -> WsoT[n<512][k<64]
        int j = i - 294912; int k = j >> 9, n = j & 511;
        WsoT[n * 64 + swzcol(n, k)] = f2bf(W_so[j]);
    } else if (i < 589824) {                // W_out 512x512 -> WoutT[n][k]
        int j = i - 327680; int k = j >> 9, n = j & 511;
        WoutT[n * 512 + swzcol(n, k)] = f2bf(W_out[j]);
    }
}

// ---------------- LayerNorm: one wave per row, pre-swizzled bf16 out -----------
__global__ __launch_bounds__(64) void ln_kernel(const float* __restrict__ x,
                                                const float* __restrict__ gamma,
                                                const float* __restrict__ beta,
                                                unsigned short* __restrict__ xn)
{
    size_t row = blockIdx.x;
    int lane = threadIdx.x;                       // 0..63, covers cols lane*8..+7
    const float4* xr = (const float4*)(x + row * DM);
    float4 v0 = xr[lane * 2];
    float4 v1 = xr[lane * 2 + 1];
    float s  = v0.x + v0.y + v0.z + v0.w + v1.x + v1.y + v1.z + v1.w;
    float s2 = v0.x*v0.x + v0.y*v0.y + v0.z*v0.z + v0.w*v0.w
             + v1.x*v1.x + v1.y*v1.y + v1.z*v1.z + v1.w*v1.w;
    #pragma unroll
    for (int off = 32; off > 0; off >>= 1) {
        s  += __shfl_xor(s,  off);
        s2 += __shfl_xor(s2, off);
    }
    float mu  = s * (1.0f / DM);
    float var = s2 * (1.0f / DM) - mu * mu;
    float rs  = rsqrtf(var + LN_EPS);
    const float4* g4 = (const float4*)gamma;
    const float4* b4 = (const float4*)beta;
    float4 g0 = g4[lane * 2], g1 = g4[lane * 2 + 1];
    float4 bb0 = b4[lane * 2], bb1 = b4[lane * 2 + 1];
    short8 o;
    o[0] = (short)f2bf((v0.x - mu) * rs * g0.x + bb0.x);
    o[1] = (short)f2bf((v0.y - mu) * rs * g0.y + bb0.y);
    o[2] = (short)f2bf((v0.z - mu) * rs * g0.z + bb0.z);
    o[3] = (short)f2bf((v0.w - mu) * rs * g0.w + bb0.w);
    o[4] = (short)f2bf((v1.x - mu) * rs * g1.x + bb1.x);
    o[5] = (short)f2bf((v1.y - mu) * rs * g1.y + bb1.y);
    o[6] = (short)f2bf((v1.z - mu) * rs * g1.z + bb1.z);
    o[7] = (short)f2bf((v1.w - mu) * rs * g1.w + bb1.w);
    int g = (lane & 7) ^ ((int)row & 7);          // swizzled granule
    *(short8*)(xn + row * DM + (lane >> 3) * 64 + g * 8) = o;
}

// ---------------- epilogue helpers ----------------
__device__ __forceinline__ float aux_to_float(float x) { return x; }
__device__ __forceinline__ float aux_to_float(bf16 x)  { return __bfloat162float(x); }
__device__ __forceinline__ void store_out(float* C, size_t i, float v) { C[i] = v; }
__device__ __forceinline__ void store_out(bf16* C, size_t i, float v)  { C[i] = __float2bfloat16(v); }

// ---------------- counted-vmcnt pipelined MFMA GEMM (T3-min + T4) ----------------
// C = A(MxK) @ BT^T (BT is NxK) + epilogue. A, BT pre-swizzled bf16.
// BM=128, BK=64, 512 threads (8 waves, WR x WC), double-buffered LDS,
// raw barriers + counted vmcnt (queue never drains to 0 in main loop),
// aux/residual stream prefetched after the last stage.
template<int BN, int WR, int WC, typename OutT, typename AuxT,
         bool HB, bool HA, bool HS, bool SWZO, bool AUXSWZ>
__global__ __launch_bounds__(512, 4) void gemm_pipe(const unsigned short* __restrict__ A,
                                                    const unsigned short* __restrict__ BT,
                                                    const float* __restrict__ bias,
                                                    const AuxT* __restrict__ aux,
                                                    const float* __restrict__ scale,
                                                    OutT* __restrict__ C,
                                                    int M, int N, int K)
{
    constexpr int BM = 128, BK = 64;
    constexpr int MF = BM / (16 * WR), NF = BN / (16 * WC);
    constexpr int ABYTES = BM * 128;          // BK=64 -> 128 B/row
    constexpr int BBYTES = BN * 128;
    constexpr int AIN = ABYTES / 8192;        // 512 thr x 16 B = 8 KB per instr
    constexpr int BIN = BBYTES / 8192;
    constexpr int LPS = AIN + BIN;            // loads per stage per thread
    constexpr int AUXN = HA ? MF * NF * 4 : 0;
    __shared__ unsigned char LDS[2][ABYTES + BBYTES];

    const int tid = threadIdx.x;
    const int lane = tid & 63, w = tid >> 6;
    const int fr = lane & 15, fq = lane >> 4;
    const int wr = w % WR, wc = w / WR;

    // XCD-aware swizzle (T1), N-fastest so A-tile reuse stays on one XCD.
    const int ny = N / BN;
    const int per = (int)gridDim.x >> 3;      // gridDim.x % 8 == 0 for all uses
    const int lg = ((int)blockIdx.x & 7) * per + ((int)blockIdx.x >> 3);
    const size_t bm0 = (size_t)(lg / ny) * BM;
    const int bn0 = (lg % ny) * BN;
    const int nk = K / BK;

    f32x4 acc[MF][NF];
    #pragma unroll
    for (int m = 0; m < MF; ++m)
        #pragma unroll
        for (int n = 0; n < NF; ++n)
            acc[m][n] = (f32x4){0.f, 0.f, 0.f, 0.f};

    float paux[MF > 0 ? MF : 1][NF > 0 ? NF : 1][4];

    auto stage = [&](int buf, int k0) {
        #pragma unroll
        for (int j = 0; j < AIN; ++j) {
            int row = j * 64 + (tid >> 3);                      // per-lane global addr
            gload_lds16(A + (bm0 + row) * (size_t)K + (size_t)k0 * 64 + (tid & 7) * 8,
                        &LDS[buf][j * 8192 + w * 1024]);        // wave-uniform LDS base
        }
        #pragma unroll
        for (int j = 0; j < BIN; ++j) {
            int row = j * 64 + (tid >> 3);
            gload_lds16(BT + (size_t)(bn0 + row) * K + (size_t)k0 * 64 + (tid & 7) * 8,
                        &LDS[buf][ABYTES + j * 8192 + w * 1024]);
        }
    };

    auto prefetch_aux = [&]() {
        if constexpr (HA) {
            #pragma unroll
            for (int n = 0; n < NF; ++n) {
                int coll = wc * (BN / WC) + n * 16 + fr;
                int colg = bn0 + coll;
                #pragma unroll
                for (int m = 0; m < MF; ++m) {
                    int rowl = wr * (BM / WR) + m * 16 + fq * 4;
                    #pragma unroll
                    for (int r = 0; r < 4; ++r) {
                        size_t ac = AUXSWZ ? (size_t)swzcol(rowl + r, colg) : (size_t)colg;
                        paux[m][n][r] = aux_to_float(aux[(bm0 + rowl + r) * (size_t)N + ac]);
                    }
                }
            }
        }
    };

    auto compute = [&](int buf) {
        #pragma unroll
        for (int h = 0; h < 2; ++h) {                           // two K=32 slices
            short8 af[MF], bfr[NF];
            #pragma unroll
            for (int m = 0; m < MF; ++m) {
                int row = wr * (BM / WR) + m * 16 + fr;
                int g = (h * 4 + fq) ^ (row & 7);
                af[m] = *(const short8*)&LDS[buf][row * 128 + g * 16];
            }
            #pragma unroll
            for (int n = 0; n < NF; ++n) {
                int col = wc * (BN / WC) + n * 16 + fr;
                int g = (h * 4 + fq) ^ (col & 7);
                bfr[n] = *(const short8*)&LDS[buf][ABYTES + col * 128 + g * 16];
            }
            #pragma unroll
            for (int m = 0; m < MF; ++m)
                #pragma unroll
                for (int n = 0; n < NF; ++n)
                    acc[m][n] = __builtin_amdgcn_mfma_f32_16x16x32_bf16(af[m], bfr[n], acc[m][n], 0, 0, 0);
        }
    };

    // prologue
    stage(0, 0);
    if (HA && nk == 1) prefetch_aux();
    int cur = 0;
    for (int t = 0; t < nk; ++t) {
        const bool hasNext = (t + 1 < nk);
        if (hasNext) {
            stage(cur ^ 1, t + 1);
            if (HA && t + 2 == nk) prefetch_aux();   // issue aux after last stage
        }
        // wait until tile t's loads have landed; newer loads stay in flight
        if constexpr (HA) {
            if (t < nk - 2)       wait_vm<LPS>();
            else if (t == nk - 2) wait_vm<LPS + AUXN>();
            else                  wait_vm<AUXN>();
        } else {
            if (hasNext) wait_vm<LPS>();
            else         wait_vm<0>();
        }
        block_barrier();                 // all threads' t-loads now visible
        compute(cur);
        if (hasNext) {
            block_barrier();             // all waves done reading buf before overwrite
            cur ^= 1;
        }
    }

    // epilogue
    #pragma unroll
    for (int n = 0; n < NF; ++n) {
        int coll = wc * (BN / WC) + n * 16 + fr;
        int colg = bn0 + coll;
        float bv = HB ? bias[colg] : 0.f;
        float sv = HS ? scale[colg] : 1.f;
        #pragma unroll
        for (int m = 0; m < MF; ++m) {
            int rowl = wr * (BM / WR) + m * 16 + fq * 4;
            #pragma unroll
            for (int r = 0; r < 4; ++r) {
                size_t row = bm0 + rowl + r;
                float v = acc[m][n][r] + bv;
                if constexpr (HA) v += sv * paux[m][n][r];
                size_t oc = SWZO ? (size_t)swzcol(rowl + r, colg) : (size_t)colg;
                store_out(C, row * (size_t)N + oc, v);
            }
        }
    }
}

// ---------------- SSM scan (chunked, 3 passes) ----------------
__device__ __forceinline__ void ssm_params(const float* A_log, const float* log_delta,
                                           const float* Bv, int n, float& Ab, float& Bb)
{
    float A  = -expf(A_log[n]);
    float dl = log1pf(expf(log_delta[n]));   // softplus
    float dA2 = dl * A * 0.5f;
    float inv = 1.0f / (1.0f - dA2);
    Ab = (1.0f + dA2) * inv;
    Bb = dl * inv * Bv[n];
}

__global__ __launch_bounds__(64) void scan_pass1(const float* __restrict__ xs,
                                                 const float* __restrict__ A_log,
                                                 const float* __restrict__ log_delta,
                                                 const float* __restrict__ Bv,
                                                 float* __restrict__ carry)
{
    int b = blockIdx.x / NCHUNK;
    int c = blockIdx.x % NCHUNK;
    int n = threadIdx.x;
    float Ab, Bb;
    ssm_params(A_log, log_delta, Bv, n, Ab, Bb);
    size_t base = ((size_t)b * L_SEQ + (size_t)c * LCH) * DS + n;
    float h = 0.0f;
    for (int t = 0; t < LCH; ++t)
        h = Ab * h + Bb * xs[base + (size_t)t * DS];
    carry[((size_t)b * NCHUNK + c) * DS + n] = h;
}

__global__ __launch_bounds__(64) void scan_pass2(const float* __restrict__ A_log,
                                                 const float* __restrict__ log_delta,
                                                 const float* __restrict__ Bv,
                                                 const float* __restrict__ carry,
                                                 float* __restrict__ hin)
{
    int b = blockIdx.x;
    int n = threadIdx.x;
    float Ab, Bb;
    ssm_params(A_log, log_delta, Bv, n, Ab, Bb);
    float powA = powf(Ab, (float)LCH);
    float h = 0.0f;
    for (int c = 0; c < NCHUNK; ++c) {
        size_t idx = ((size_t)b * NCHUNK + c) * DS + n;
        hin[idx] = h;
        h = powA * h + carry[idx];
    }
}

// ys written PRE-SWIZZLED (it is the A-operand of G7)
__global__ __launch_bounds__(64) void scan_pass3(const float* __restrict__ xs,
                                                 const float* __restrict__ A_log,
                                                 const float* __restrict__ log_delta,
                                                 const float* __restrict__ Bv,
                                                 const float* __restrict__ Cv,
                                                 const float* __restrict__ hin,
                                                 unsigned short* __restrict__ ys)
{
    int b = blockIdx.x / NCHUNK;
    int c = blockIdx.x % NCHUNK;
    int n = threadIdx.x;
    float Ab, Bb;
    ssm_params(A_log, log_delta, Bv, n, Ab, Bb);
    float Cn = Cv[n];
    size_t base = ((size_t)b * L_SEQ + (size_t)c * LCH) * DS + n;
    size_t rowbase = ((size_t)b * L_SEQ + (size_t)c * LCH) * DS;
    float h = hin[((size_t)b * NCHUNK + c) * DS + n];
    for (int t = 0; t < LCH; ++t) {
        h = Ab * h + Bb * xs[base + (size_t)t * DS];
        int col = (((n >> 3) ^ (t & 7)) << 3) | (n & 7);   // row&7 == t&7 (LCH%8==0)
        ys[rowbase + (size_t)t * DS + col] = f2bf(Cn * h);
    }
}

// ---------------- launcher ----------------
extern "C" void kernel_launch(void* const* d_in, const int* in_sizes, int n_in,
                              void* d_out, int out_size, void* d_ws, size_t ws_size,
                              hipStream_t stream)
{
    const float* x         = (const float*)d_in[0];
    const float* ln_gamma  = (const float*)d_in[1];
    const float* ln_beta   = (const float*)d_in[2];
    const float* W_in      = (const float*)d_in[3];
    const float* b_in      = (const float*)d_in[4];
    const float* W_xs      = (const float*)d_in[5];
    const float* A_log     = (const float*)d_in[6];
    const float* log_delta = (const float*)d_in[7];
    const float* Bv        = (const float*)d_in[8];
    const float* Cv        = (const float*)d_in[9];
    const float* Dv        = (const float*)d_in[10];
    const float* W_so      = (const float*)d_in[11];
    const float* W_out     = (const float*)d_in[12];
    const float* b_out     = (const float*)d_in[13];
    float* out = (float*)d_out;

    const size_t M = M_ROWS;
    float*          xs_f = (float*)d_ws;                      // M*64 f32
    unsigned short* xn_b = (unsigned short*)(xs_f + M * DS);  // M*512 bf16 (reused as t1)
    unsigned short* z_b  = xn_b + M * (size_t)DM;             // M*512 bf16
    unsigned short* ys_b = z_b + M * (size_t)DM;              // M*64 bf16
    unsigned short* WinT = ys_b + M * (size_t)DS;             // 512*512
    unsigned short* WxsT = WinT + (size_t)DM * DM;            // 64*512
    unsigned short* WsoT = WxsT + (size_t)DS * DM;            // 512*64
    unsigned short* WoutT= WsoT + (size_t)DM * DS;            // 512*512
    float* carry = (float*)(WoutT + (size_t)DM * DM);         // 8*256*64
    float* hin   = carry + NB * NCHUNK * DS;                  // 8*256*64
    unsigned short* t1_b = xn_b;                              // xn dead after G2

    wtrans_all<<<dim3(589824 / 256), dim3(256), 0, stream>>>(W_in, W_xs, W_so, W_out,
                                                             WinT, WxsT, WsoT, WoutT);
    // LN -> xn (pre-swizzled bf16)
    ln_kernel<<<dim3((unsigned)M), dim3(64), 0, stream>>>(x, ln_gamma, ln_beta, xn_b);
    // G2: z = xn @ W_in + b_in   (bf16, pre-swizzled out)
    gemm_pipe<128, 2, 4, bf16, float, true, false, false, true, false>
        <<<dim3((M / 128) * (DM / 128)), dim3(512), 0, stream>>>(xn_b, WinT, b_in, nullptr, nullptr,
                                                                 (bf16*)z_b, (int)M, DM, DM);
    // G3: xs = z @ W_xs          (f32 out, plain)
    gemm_pipe<64, 4, 2, float, float, false, false, false, false, false>
        <<<dim3(M / 128), dim3(512), 0, stream>>>(z_b, WxsT, nullptr, nullptr, nullptr,
                                                  xs_f, (int)M, DS, DM);
    // scan
    scan_pass1<<<dim3(NB * NCHUNK), dim3(64), 0, stream>>>(xs_f, A_log, log_delta, Bv, carry);
    scan_pass2<<<dim3(NB), dim3(64), 0, stream>>>(A_log, log_delta, Bv, carry, hin);
    scan_pass3<<<dim3(NB * NCHUNK), dim3(64), 0, stream>>>(xs_f, A_log, log_delta, Bv, Cv, hin, ys_b);
    // G7: t1 = ys @ W_so + D*z   (K=64 -> nk=1; bf16 pre-swizzled out; z aux de-swizzled)
    gemm_pipe<128, 2, 4, bf16, bf16, false, true, true, true, true>
        <<<dim3((M / 128) * (DM / 128)), dim3(512), 0, stream>>>(ys_b, WsoT, nullptr, (const bf16*)z_b,
                                                                 Dv, (bf16*)t1_b, (int)M, DM, DS);
    // G8: out = t1 @ W_out + b_out + x  (f32 out, plain)
    gemm_pipe<128, 2, 4, float, float, true, true, false, false, false>
        <<<dim3((M / 128) * (DM / 128)), dim3(512), 0, stream>>>(t1_b, WoutT, b_out, x, nullptr,
                                                                 out, (int)M, DM, DM);
}